// Round 1
// baseline (15281.377 us; speedup 1.0000x reference)
//
#include <hip/hip_runtime.h>
#include <math.h>

#define DEV static __device__ __forceinline__

// Exact-IEEE squared distance, same op order as the numpy/XLA reference:
// ((dx*dx + dy*dy) + dz*dz), no FMA contraction.
DEV float sqd(float ax, float ay, float az, float bx, float by, float bz) {
    float dx = __fsub_rn(ax, bx), dy = __fsub_rn(ay, by), dz = __fsub_rn(az, bz);
    return __fadd_rn(__fadd_rn(__fmul_rn(dx, dx), __fmul_rn(dy, dy)), __fmul_rn(dz, dz));
}

// ---------------------------------------------------------------------------
// Radius neighbors: for each point i in cloud b, the (up to) 32 nearest
// neighbors with d2 <= rr (excluding self), ties -> lower index (stable, like
// lax.top_k). Output row of 33 ints: packed neighbors, then self, then -1.
// ---------------------------------------------------------------------------
__global__ __launch_bounds__(256) void radius_kernel(
        const float* __restrict__ pos, int N, float rr, int* __restrict__ idx_out) {
    __shared__ float sp[2048 * 3];
    int b = blockIdx.x;
    const float* p = pos + (size_t)b * N * 3;
    for (int t = threadIdx.x; t < N * 3; t += 256) sp[t] = p[t];
    __syncthreads();
    int i = blockIdx.y * 256 + threadIdx.x;
    if (i >= N) return;
    float qx = sp[i * 3 + 0], qy = sp[i * 3 + 1], qz = sp[i * 3 + 2];
    float bd[32];
    int bi[32];
#pragma unroll
    for (int t = 0; t < 32; t++) { bd[t] = INFINITY; bi[t] = -1; }
    for (int j = 0; j < N; j++) {
        float d2 = sqd(sp[j * 3 + 0], sp[j * 3 + 1], sp[j * 3 + 2], qx, qy, qz);
        // strict < on bd[31]: an equal-distance later index never displaces
        if (j != i && d2 <= rr && d2 < bd[31]) {
            int rank = 0;
#pragma unroll
            for (int t = 0; t < 32; t++) rank += (bd[t] <= d2) ? 1 : 0;  // stable: equals stay in front
#pragma unroll
            for (int t = 31; t >= 1; t--) {
                bool mv = (t > rank);
                bd[t] = mv ? bd[t - 1] : bd[t];
                bi[t] = mv ? bi[t - 1] : bi[t];
            }
#pragma unroll
            for (int t = 0; t < 32; t++)
                if (t == rank) { bd[t] = d2; bi[t] = j; }
        }
    }
    int* o = idx_out + ((size_t)b * N + i) * 33;
    int c = 0;
#pragma unroll
    for (int t = 0; t < 32; t++) c += (bi[t] >= 0) ? 1 : 0;
#pragma unroll
    for (int t = 0; t < 32; t++) o[t] = (t < c) ? bi[t] : ((t == c) ? i : -1);
    o[32] = (c == 32) ? i : -1;
}

// ---------------------------------------------------------------------------
// Stage-1 conv (feats = rel[3] -> 64 -> 64, masked max over neighbors, relu).
// One wave per point; W1b column lives in 64 VGPRs; hidden broadcast via shfl.
// ---------------------------------------------------------------------------
__global__ __launch_bounds__(64) void conv1_kernel(
        const float* __restrict__ pos, const int* __restrict__ idx,
        const float* __restrict__ W1a, const float* __restrict__ b1a,
        const float* __restrict__ W1b, const float* __restrict__ b1b,
        float* __restrict__ x1) {
    int pid = blockIdx.x;               // b*2048 + i
    int b = pid >> 11, i = pid & 2047;
    int lane = threadIdx.x;
    const float* p = pos + (size_t)b * 2048 * 3;
    const int* row = idx + (size_t)pid * 33;
    float wa0 = W1a[lane], wa1 = W1a[64 + lane], wa2 = W1a[128 + lane];
    float ba = b1a[lane], bb = b1b[lane];
    float wb[64];
#pragma unroll
    for (int c = 0; c < 64; c++) wb[c] = W1b[c * 64 + lane];
    float qx = p[i * 3 + 0], qy = p[i * 3 + 1], qz = p[i * 3 + 2];
    float best = -INFINITY;
    for (int s = 0; s < 33; s++) {
        int j = row[s];
        if (j < 0) continue;            // uniform across the wave
        float rx = __fsub_rn(p[j * 3 + 0], qx);
        float ry = __fsub_rn(p[j * 3 + 1], qy);
        float rz = __fsub_rn(p[j * 3 + 2], qz);
        float h1 = fmaf(rz, wa2, fmaf(ry, wa1, fmaf(rx, wa0, ba)));
        h1 = fmaxf(h1, 0.f);
        float acc = bb;
#pragma unroll
        for (int c = 0; c < 64; c++) acc = fmaf(__shfl(h1, c, 64), wb[c], acc);
        best = fmaxf(best, acc);
    }
    x1[(size_t)pid * 64 + lane] = fmaxf(best, 0.f);
}

// ---------------------------------------------------------------------------
// Farthest point sampling: one 256-thread block per cloud, deterministic
// start at 0, argmax ties -> lowest index (matches jnp.argmax).
// ---------------------------------------------------------------------------
template <int N, int M, int PT>
__global__ __launch_bounds__(256) void fps_kernel(
        const float* __restrict__ pos, int* __restrict__ s_out) {
    __shared__ float sp[N * 3];
    __shared__ float swv[4];
    __shared__ int swi[4];
    __shared__ float selp[3];
    int b = blockIdx.x;
    const float* p = pos + (size_t)b * N * 3;
    int t = threadIdx.x;
    for (int u = t; u < N * 3; u += 256) sp[u] = p[u];
    __syncthreads();
    float d[PT];
    float x0 = sp[0], y0 = sp[1], z0 = sp[2];
#pragma unroll
    for (int q = 0; q < PT; q++) {
        int j = q * 256 + t;
        d[q] = sqd(sp[j * 3], sp[j * 3 + 1], sp[j * 3 + 2], x0, y0, z0);
    }
    int* so = s_out + b * M;
    if (t == 0) so[0] = 0;
    for (int m = 1; m < M; m++) {
        float bv = d[0];
        int bj = t;
#pragma unroll
        for (int q = 1; q < PT; q++) {
            int j = q * 256 + t;
            if (d[q] > bv) { bv = d[q]; bj = j; }   // strict > : lowest index kept
        }
#pragma unroll
        for (int off = 32; off >= 1; off >>= 1) {
            float ov = __shfl_xor(bv, off, 64);
            int oj = __shfl_xor(bj, off, 64);
            if (ov > bv || (ov == bv && oj < bj)) { bv = ov; bj = oj; }
        }
        int w = t >> 6;
        if ((t & 63) == 0) { swv[w] = bv; swi[w] = bj; }
        __syncthreads();
        if (t == 0) {
            float v = swv[0];
            int j = swi[0];
            for (int ww = 1; ww < 4; ww++)
                if (swv[ww] > v || (swv[ww] == v && swi[ww] < j)) { v = swv[ww]; j = swi[ww]; }
            so[m] = j;
            selp[0] = sp[j * 3]; selp[1] = sp[j * 3 + 1]; selp[2] = sp[j * 3 + 2];
        }
        __syncthreads();
        float sx = selp[0], sy = selp[1], sz = selp[2];
#pragma unroll
        for (int q = 0; q < PT; q++) {
            int j = q * 256 + t;
            float di = sqd(sp[j * 3], sp[j * 3 + 1], sp[j * 3 + 2], sx, sy, sz);
            d[q] = fminf(d[q], di);
        }
    }
}

// ---------------------------------------------------------------------------
// Gather sampled positions + features.
// ---------------------------------------------------------------------------
__global__ void gather_kernel(
        const float* __restrict__ pos_in, const float* __restrict__ x_in,
        const int* __restrict__ s, int Nin, int M, int C,
        float* __restrict__ pos_out, float* __restrict__ x_out) {
    int b = blockIdx.y, m = blockIdx.x, t = threadIdx.x;
    int j = s[b * M + m];
    x_out[((size_t)b * M + m) * C + t] = x_in[((size_t)b * Nin + j) * C + t];
    if (t < 3) pos_out[((size_t)b * M + m) * 3 + t] = pos_in[((size_t)b * Nin + j) * 3 + t];
}

// ---------------------------------------------------------------------------
// Stage-2/3 conv: feats = concat(x[j], rel) [CXIN+3] -> CH -> CH,
// masked max over 33 neighbor slots, relu. One point per block.
// ---------------------------------------------------------------------------
template <int CXIN, int CH, int GRPS, int N>
__global__ __launch_bounds__(CH * GRPS) void convN_kernel(
        const float* __restrict__ posc, const float* __restrict__ xin,
        const int* __restrict__ idx,
        const float* __restrict__ Wa, const float* __restrict__ ba,
        const float* __restrict__ Wb, const float* __restrict__ bb,
        float* __restrict__ xout) {
    constexpr int CIN = CXIN + 3;
    constexpr int NTH = CH * GRPS;
    constexpr int RPG = (33 + GRPS - 1) / GRPS;
    __shared__ float F[33][CIN];
    __shared__ float H1[33][CH];
    __shared__ int sj[33];
    __shared__ float part[GRPS][CH];
    int pid = blockIdx.x;               // b*N + i
    int b = pid / N, i = pid - b * N;
    int tid = threadIdx.x;
    int g = tid / CH, c = tid % CH;
    const float* p = posc + (size_t)b * N * 3;
    const int* row = idx + (size_t)pid * 33;
    if (tid < 33) sj[tid] = row[tid];
    __syncthreads();
    float qx = p[i * 3 + 0], qy = p[i * 3 + 1], qz = p[i * 3 + 2];
    for (int e = tid; e < 33 * CIN; e += NTH) {
        int r = e / CIN, f = e - r * CIN;
        int j = sj[r];
        float v = 0.f;
        if (j >= 0) {
            if (f < CXIN) {
                v = xin[((size_t)b * N + j) * CXIN + f];
            } else {
                int a = f - CXIN;
                float qa = (a == 0) ? qx : ((a == 1) ? qy : qz);
                v = __fsub_rn(p[j * 3 + a], qa);
            }
        }
        F[r][f] = v;
    }
    __syncthreads();
    // GEMM1: H1 = relu(F @ Wa + ba)
    float bav = ba[c];
    float acc[RPG];
#pragma unroll
    for (int r = 0; r < RPG; r++) acc[r] = bav;
    for (int f = 0; f < CIN; f++) {
        float w = Wa[f * CH + c];
#pragma unroll
        for (int r = 0; r < RPG; r++) {
            int rr = g * RPG + r;
            if (rr < 33) acc[r] = fmaf(F[rr][f], w, acc[r]);
        }
    }
#pragma unroll
    for (int r = 0; r < RPG; r++) {
        int rr = g * RPG + r;
        if (rr < 33) H1[rr][c] = fmaxf(acc[r], 0.f);
    }
    __syncthreads();
    // GEMM2: out = H1 @ Wb + bb, masked max over valid rows
    float bbv = bb[c];
    float acc2[RPG];
#pragma unroll
    for (int r = 0; r < RPG; r++) acc2[r] = bbv;
    for (int k = 0; k < CH; k++) {
        float w = Wb[k * CH + c];
#pragma unroll
        for (int r = 0; r < RPG; r++) {
            int rr = g * RPG + r;
            if (rr < 33) acc2[r] = fmaf(H1[rr][k], w, acc2[r]);
        }
    }
    float best = -INFINITY;
#pragma unroll
    for (int r = 0; r < RPG; r++) {
        int rr = g * RPG + r;
        if (rr < 33 && sj[rr] >= 0) best = fmaxf(best, acc2[r]);
    }
    if constexpr (GRPS > 1) {
        part[g][c] = best;
        __syncthreads();
        if (g == 0) {
#pragma unroll
            for (int gg = 1; gg < GRPS; gg++) best = fmaxf(best, part[gg][c]);
        }
    }
    if (g == 0) xout[(size_t)pid * CH + c] = fmaxf(best, 0.f);
}

// ---------------------------------------------------------------------------
// Global max pool + MLP head + log_softmax. One block per cloud.
// ---------------------------------------------------------------------------
__global__ __launch_bounds__(256) void head_kernel(
        const float* __restrict__ x3,
        const float* __restrict__ Wl1, const float* __restrict__ bl1,
        const float* __restrict__ Wl2, const float* __restrict__ bl2,
        const float* __restrict__ Wl3, const float* __restrict__ bl3,
        float* __restrict__ out) {
    __shared__ float gbuf[256], h1[256], h2[256], h3[40];
    int b = blockIdx.x, c = threadIdx.x;
    const float* xb = x3 + (size_t)b * 256 * 256;
    float m = -INFINITY;
    for (int r = 0; r < 256; r++) m = fmaxf(m, xb[r * 256 + c]);
    gbuf[c] = m;
    __syncthreads();
    float a = bl1[c];
    for (int k = 0; k < 256; k++) a = fmaf(gbuf[k], Wl1[k * 256 + c], a);
    h1[c] = fmaxf(a, 0.f);
    __syncthreads();
    a = bl2[c];
    for (int k = 0; k < 256; k++) a = fmaf(h1[k], Wl2[k * 256 + c], a);
    h2[c] = fmaxf(a, 0.f);
    __syncthreads();
    if (c < 40) {
        a = bl3[c];
        for (int k = 0; k < 256; k++) a = fmaf(h2[k], Wl3[k * 40 + c], a);
        h3[c] = a;
    }
    __syncthreads();
    if (c < 64) {
        float v = -INFINITY;
        if (c < 40) v = h3[c];
        float mx = v;
#pragma unroll
        for (int off = 32; off >= 1; off >>= 1) mx = fmaxf(mx, __shfl_xor(mx, off, 64));
        float e = (c < 40) ? expf(__fsub_rn(v, mx)) : 0.f;
        float s = e;
#pragma unroll
        for (int off = 32; off >= 1; off >>= 1) s = __fadd_rn(s, __shfl_xor(s, off, 64));
        float ls = logf(s);
        if (c < 40) out[b * 40 + c] = __fsub_rn(__fsub_rn(v, mx), ls);
    }
}

// ---------------------------------------------------------------------------
extern "C" void kernel_launch(void* const* d_in, const int* in_sizes, int n_in,
                              void* d_out, int out_size, void* d_ws, size_t ws_size,
                              hipStream_t stream) {
    (void)in_sizes; (void)n_in; (void)out_size; (void)ws_size;
    const float* pos = (const float*)d_in[0];
    // d_in[1] = batch (int64) — layout is uniform, unused
    const float* W1a = (const float*)d_in[2];
    const float* b1a = (const float*)d_in[3];
    const float* W1b = (const float*)d_in[4];
    const float* b1b = (const float*)d_in[5];
    const float* W2a = (const float*)d_in[6];
    const float* b2a = (const float*)d_in[7];
    const float* W2b = (const float*)d_in[8];
    const float* b2b = (const float*)d_in[9];
    const float* W3a = (const float*)d_in[10];
    const float* b3a = (const float*)d_in[11];
    const float* W3b = (const float*)d_in[12];
    const float* b3b = (const float*)d_in[13];
    const float* Wl1 = (const float*)d_in[14];
    const float* bl1 = (const float*)d_in[15];
    const float* Wl2 = (const float*)d_in[16];
    const float* bl2 = (const float*)d_in[17];
    const float* Wl3 = (const float*)d_in[18];
    const float* bl3 = (const float*)d_in[19];
    float* out = (float*)d_out;

    const int B = 32;
    char* w = (char*)d_ws;
    auto alloc = [&](size_t bytes) -> char* {
        char* r = w;
        w += (bytes + 255) & ~(size_t)255;
        return r;
    };
    int*   idx1 = (int*)  alloc((size_t)B * 2048 * 33 * 4);
    float* x1   = (float*)alloc((size_t)B * 2048 * 64 * 4);
    int*   s1   = (int*)  alloc((size_t)B * 1024 * 4);
    float* pos2 = (float*)alloc((size_t)B * 1024 * 3 * 4);
    float* x2in = (float*)alloc((size_t)B * 1024 * 64 * 4);
    int*   idx2 = (int*)  alloc((size_t)B * 1024 * 33 * 4);
    float* x2   = (float*)alloc((size_t)B * 1024 * 128 * 4);
    int*   s2   = (int*)  alloc((size_t)B * 256 * 4);
    float* pos3 = (float*)alloc((size_t)B * 256 * 3 * 4);
    float* x3in = (float*)alloc((size_t)B * 256 * 128 * 4);
    int*   idx3 = (int*)  alloc((size_t)B * 256 * 33 * 4);
    float* x3   = (float*)alloc((size_t)B * 256 * 256 * 4);

    // ---- SA module 1 (2048 pts, r=0.2) ----
    radius_kernel<<<dim3(B, 8), 256, 0, stream>>>(pos, 2048, 0.04f, idx1);
    conv1_kernel<<<B * 2048, 64, 0, stream>>>(pos, idx1, W1a, b1a, W1b, b1b, x1);
    fps_kernel<2048, 1024, 8><<<B, 256, 0, stream>>>(pos, s1);
    gather_kernel<<<dim3(1024, B), 64, 0, stream>>>(pos, x1, s1, 2048, 1024, 64, pos2, x2in);

    // ---- SA module 2 (1024 pts, r=0.4) ----
    radius_kernel<<<dim3(B, 4), 256, 0, stream>>>(pos2, 1024, 0.16f, idx2);
    convN_kernel<64, 128, 2, 1024><<<B * 1024, 256, 0, stream>>>(
        pos2, x2in, idx2, W2a, b2a, W2b, b2b, x2);
    fps_kernel<1024, 256, 4><<<B, 256, 0, stream>>>(pos2, s2);
    gather_kernel<<<dim3(256, B), 128, 0, stream>>>(pos2, x2, s2, 1024, 256, 128, pos3, x3in);

    // ---- SA module 3 (256 pts, r=1.0) ----
    radius_kernel<<<dim3(B, 1), 256, 0, stream>>>(pos3, 256, 1.0f, idx3);
    convN_kernel<128, 256, 1, 256><<<B * 256, 256, 0, stream>>>(
        pos3, x3in, idx3, W3a, b3a, W3b, b3b, x3);

    // ---- global pool + head ----
    head_kernel<<<B, 256, 0, stream>>>(x3, Wl1, bl1, Wl2, bl2, Wl3, bl3, out);
}

// Round 2
// 6048.708 us; speedup vs baseline: 2.5264x; 2.5264x over previous
//
#include <hip/hip_runtime.h>
#include <math.h>

#define DEV static __device__ __forceinline__

typedef short s8v  __attribute__((ext_vector_type(8)));   // 8 bf16 (A/B frag)
typedef short s4v  __attribute__((ext_vector_type(4)));
typedef float f4v  __attribute__((ext_vector_type(4)));   // C/D frag

// round-to-nearest-even f32 -> bf16 (bits in a short)
DEV short bf16rne(float f) {
    unsigned u = __float_as_uint(f);
    unsigned r = (u + 0x7fffu + ((u >> 16) & 1u)) >> 16;
    return (short)r;
}

// Exact-IEEE squared distance, same op order as the numpy/XLA reference.
DEV float sqd(float ax, float ay, float az, float bx, float by, float bz) {
    float dx = __fsub_rn(ax, bx), dy = __fsub_rn(ay, by), dz = __fsub_rn(az, bz);
    return __fadd_rn(__fadd_rn(__fmul_rn(dx, dx), __fmul_rn(dy, dy)), __fmul_rn(dz, dz));
}

// ---------------------------------------------------------------------------
// Radius neighbors (fp32 exact; selection must match reference bit-for-bit).
// Row of 33 ints: packed neighbors (nearest-first, ties->lower idx), self, -1.
// ---------------------------------------------------------------------------
__global__ __launch_bounds__(256) void radius_kernel(
        const float* __restrict__ pos, int N, float rr, int* __restrict__ idx_out) {
    __shared__ float sp[2048 * 3];
    int b = blockIdx.x;
    const float* p = pos + (size_t)b * N * 3;
    for (int t = threadIdx.x; t < N * 3; t += 256) sp[t] = p[t];
    __syncthreads();
    int i = blockIdx.y * 256 + threadIdx.x;
    if (i >= N) return;
    float qx = sp[i * 3 + 0], qy = sp[i * 3 + 1], qz = sp[i * 3 + 2];
    float bd[32];
    int bi[32];
#pragma unroll
    for (int t = 0; t < 32; t++) { bd[t] = INFINITY; bi[t] = -1; }
    for (int j = 0; j < N; j++) {
        float d2 = sqd(sp[j * 3 + 0], sp[j * 3 + 1], sp[j * 3 + 2], qx, qy, qz);
        if (j != i && d2 <= rr && d2 < bd[31]) {
            int rank = 0;
#pragma unroll
            for (int t = 0; t < 32; t++) rank += (bd[t] <= d2) ? 1 : 0;
#pragma unroll
            for (int t = 31; t >= 1; t--) {
                bool mv = (t > rank);
                bd[t] = mv ? bd[t - 1] : bd[t];
                bi[t] = mv ? bi[t - 1] : bi[t];
            }
#pragma unroll
            for (int t = 0; t < 32; t++)
                if (t == rank) { bd[t] = d2; bi[t] = j; }
        }
    }
    int* o = idx_out + ((size_t)b * N + i) * 33;
    int c = 0;
#pragma unroll
    for (int t = 0; t < 32; t++) c += (bi[t] >= 0) ? 1 : 0;
#pragma unroll
    for (int t = 0; t < 32; t++) o[t] = (t < c) ? bi[t] : ((t == c) ? i : -1);
    o[32] = (c == 32) ? i : -1;
}

// ---------------------------------------------------------------------------
// Weight pre-pack: W [K x C] f32 row-major -> bf16 A-fragments of W^T for
// mfma_f32_16x16x32_bf16. Layout: frag[mt][ks][lane][j]:
//   c = 16*mt + (lane&15), k = 32*ks + (lane>>4)*8 + j, elem = W[k*C+c] (0 pad).
// ---------------------------------------------------------------------------
__global__ void pack_w_kernel(const float* __restrict__ W, short* __restrict__ out,
                              int Kreal, int C, int KS, int total) {
    int t = blockIdx.x * 256 + threadIdx.x;
    if (t >= total) return;
    int lane = t & 63;
    int mk = t >> 6;
    int ks = mk % KS, mt = mk / KS;
    int c = 16 * mt + (lane & 15);
    int k0 = 32 * ks + ((lane >> 4) << 3);
    s8v v;
#pragma unroll
    for (int j = 0; j < 8; j++) {
        int k = k0 + j;
        v[j] = (k < Kreal) ? bf16rne(W[(size_t)k * C + c]) : (short)0;
    }
    *(s8v*)(out + (size_t)t * 8) = v;
}

// ---------------------------------------------------------------------------
// Fused MFMA point-conv: out[i,:] = relu( max_valid_rows( relu(F@Wa+ba)@Wb+bb ) )
// F rows = 33 neighbor slots per point, K zero-padded to CINp.
// Transposed GEMMs: D = Wt_frag (A) x F_rows (B) so all LDS traffic is
// contiguous b128 reads / b64 writes; row strides are odd multiples of 16B.
// PPB==1: block=1 point, 4 waves split output channels.
// PPB==4: block=4 points, each wave owns one point (all channels).
// ---------------------------------------------------------------------------
template <int CXIN, int CH, int PPB, int N>
__global__ __launch_bounds__(256) void conv_mfma_kernel(
        const float* __restrict__ pos, const float* __restrict__ xin,
        const int* __restrict__ idx,
        const short* __restrict__ Wpa, const float* __restrict__ ba,
        const short* __restrict__ Wpb, const float* __restrict__ bb,
        float* __restrict__ xout) {
    constexpr int CIN  = CXIN + 3;
    constexpr int CINp = (CIN + 31) & ~31;
    constexpr int KS1  = CINp / 32, KS2 = CH / 32;
    constexpr int MT   = CH / 16;
    constexpr int MTW  = (PPB == 4) ? MT : MT / 4;   // channel tiles per wave
    constexpr int RP   = 48;                          // padded rows per point
    constexpr int NT   = 3;                           // row tiles per point
    constexpr int FS   = CINp * 2 + 16;               // F row stride (bytes), FS/16 odd
    constexpr int HS   = CH * 2 + 16;                 // H1 row stride (bytes), HS/16 odd
    __shared__ __align__(16) char Fs[PPB * RP * FS];
    __shared__ __align__(16) char Hs[PPB * RP * HS];
    __shared__ int sj[PPB * RP];

    int tid = threadIdx.x;
    int lane = tid & 63, wid = tid >> 6;
    int pid0 = blockIdx.x * PPB;

    for (int r = tid; r < PPB * RP; r += 256) {
        int p = r / RP, s = r - p * RP;
        sj[r] = (s < 33) ? idx[(size_t)(pid0 + p) * 33 + s] : -1;
    }
    __syncthreads();

    // ---- build F (gathered neighbor features, bf16, zero-padded) ----
    constexpr int FE = PPB * RP * CINp;
    for (int e = tid; e < FE; e += 256) {
        int r = e / CINp, f = e - r * CINp;
        int p = r / RP;
        int pid = pid0 + p;
        int b = pid / N, i = pid - b * N;
        int j = sj[r];
        float v = 0.f;
        if (j >= 0 && f < CIN) {
            if (f < CXIN) {
                v = xin[((size_t)b * N + j) * CXIN + f];
            } else {
                int a = f - CXIN;
                v = __fsub_rn(pos[((size_t)b * N + j) * 3 + a],
                              pos[((size_t)b * N + i) * 3 + a]);
            }
        }
        *(short*)(Fs + (size_t)r * FS + f * 2) = bf16rne(v);
    }
    __syncthreads();

    int pw  = (PPB == 4) ? wid : 0;          // point this wave works on
    int mt0 = (PPB == 4) ? 0 : wid * MTW;    // first output-channel tile
    const char* Fw = Fs + pw * RP * FS;
    char* Hw = Hs + pw * RP * HS;
    int lr = lane & 15, lg = lane >> 4;      // row-within-tile, k-group

    // ---- GEMM1: H1^T tiles = WaT x F^T ----
    f4v acc[MTW][NT];
#pragma unroll
    for (int m = 0; m < MTW; m++)
#pragma unroll
        for (int nt = 0; nt < NT; nt++)
#pragma unroll
            for (int q = 0; q < 4; q++) acc[m][nt][q] = 0.f;
#pragma unroll
    for (int ks = 0; ks < KS1; ks++) {
        s8v bfr[NT];
#pragma unroll
        for (int nt = 0; nt < NT; nt++)
            bfr[nt] = *(const s8v*)(Fw + (nt * 16 + lr) * FS + (32 * ks + lg * 8) * 2);
#pragma unroll
        for (int m = 0; m < MTW; m++) {
            s8v afr = *(const s8v*)(Wpa + (((size_t)(mt0 + m) * KS1 + ks) * 64 + lane) * 8);
#pragma unroll
            for (int nt = 0; nt < NT; nt++)
                acc[m][nt] = __builtin_amdgcn_mfma_f32_16x16x32_bf16(afr, bfr[nt], acc[m][nt], 0, 0, 0);
        }
    }
    // bias + relu -> H1 (bf16, row-major, b64 packed writes)
#pragma unroll
    for (int m = 0; m < MTW; m++) {
        int cbase = (mt0 + m) * 16 + lg * 4;
        f4v bv = *(const f4v*)(ba + cbase);
#pragma unroll
        for (int nt = 0; nt < NT; nt++) {
            s4v hq;
#pragma unroll
            for (int q = 0; q < 4; q++)
                hq[q] = bf16rne(fmaxf(acc[m][nt][q] + bv[q], 0.f));
            *(s4v*)(Hw + (nt * 16 + lr) * HS + cbase * 2) = hq;
        }
    }
    __syncthreads();

    // ---- GEMM2: out^T tiles = WbT x H1^T ----
    f4v acc2[MTW][NT];
#pragma unroll
    for (int m = 0; m < MTW; m++)
#pragma unroll
        for (int nt = 0; nt < NT; nt++)
#pragma unroll
            for (int q = 0; q < 4; q++) acc2[m][nt][q] = 0.f;
#pragma unroll
    for (int ks = 0; ks < KS2; ks++) {
        s8v bfr[NT];
#pragma unroll
        for (int nt = 0; nt < NT; nt++)
            bfr[nt] = *(const s8v*)(Hw + (nt * 16 + lr) * HS + (32 * ks + lg * 8) * 2);
#pragma unroll
        for (int m = 0; m < MTW; m++) {
            s8v afr = *(const s8v*)(Wpb + (((size_t)(mt0 + m) * KS2 + ks) * 64 + lane) * 8);
#pragma unroll
            for (int nt = 0; nt < NT; nt++)
                acc2[m][nt] = __builtin_amdgcn_mfma_f32_16x16x32_bf16(afr, bfr[nt], acc2[m][nt], 0, 0, 0);
        }
    }

    // ---- epilogue: bias, relu, masked max over valid rows, write ----
    const int* sjw = sj + pw * RP;
#pragma unroll
    for (int m = 0; m < MTW; m++) {
        int cbase = (mt0 + m) * 16 + lg * 4;
        f4v bv = *(const f4v*)(bb + cbase);
        f4v vmx;
#pragma unroll
        for (int q = 0; q < 4; q++) vmx[q] = 0.f;  // relu floor = safe neutral
#pragma unroll
        for (int nt = 0; nt < NT; nt++) {
            int s = nt * 16 + lr;
            bool valid = (s < 33) && (sjw[s] >= 0);
#pragma unroll
            for (int q = 0; q < 4; q++) {
                float v = fmaxf(acc2[m][nt][q] + bv[q], 0.f);
                if (valid) vmx[q] = fmaxf(vmx[q], v);
            }
        }
#pragma unroll
        for (int off = 1; off < 16; off <<= 1)
#pragma unroll
            for (int q = 0; q < 4; q++)
                vmx[q] = fmaxf(vmx[q], __shfl_xor(vmx[q], off, 64));
        if (lr == 0) {
            int pid = pid0 + pw;
            *(f4v*)(xout + (size_t)pid * CH + cbase) = vmx;
        }
    }
}

// ---------------------------------------------------------------------------
// Farthest point sampling (fp32 exact selection; ties -> lowest index).
// ---------------------------------------------------------------------------
template <int N, int M, int PT>
__global__ __launch_bounds__(256) void fps_kernel(
        const float* __restrict__ pos, int* __restrict__ s_out) {
    __shared__ float sp[N * 3];
    __shared__ float swv[4];
    __shared__ int swi[4];
    __shared__ float selp[3];
    int b = blockIdx.x;
    const float* p = pos + (size_t)b * N * 3;
    int t = threadIdx.x;
    for (int u = t; u < N * 3; u += 256) sp[u] = p[u];
    __syncthreads();
    float d[PT];
    float x0 = sp[0], y0 = sp[1], z0 = sp[2];
#pragma unroll
    for (int q = 0; q < PT; q++) {
        int j = q * 256 + t;
        d[q] = sqd(sp[j * 3], sp[j * 3 + 1], sp[j * 3 + 2], x0, y0, z0);
    }
    int* so = s_out + b * M;
    if (t == 0) so[0] = 0;
    for (int m = 1; m < M; m++) {
        float bv = d[0];
        int bj = t;
#pragma unroll
        for (int q = 1; q < PT; q++) {
            int j = q * 256 + t;
            if (d[q] > bv) { bv = d[q]; bj = j; }
        }
#pragma unroll
        for (int off = 32; off >= 1; off >>= 1) {
            float ov = __shfl_xor(bv, off, 64);
            int oj = __shfl_xor(bj, off, 64);
            if (ov > bv || (ov == bv && oj < bj)) { bv = ov; bj = oj; }
        }
        int w = t >> 6;
        if ((t & 63) == 0) { swv[w] = bv; swi[w] = bj; }
        __syncthreads();
        if (t == 0) {
            float v = swv[0];
            int j = swi[0];
            for (int ww = 1; ww < 4; ww++)
                if (swv[ww] > v || (swv[ww] == v && swi[ww] < j)) { v = swv[ww]; j = swi[ww]; }
            so[m] = j;
            selp[0] = sp[j * 3]; selp[1] = sp[j * 3 + 1]; selp[2] = sp[j * 3 + 2];
        }
        __syncthreads();
        float sx = selp[0], sy = selp[1], sz = selp[2];
#pragma unroll
        for (int q = 0; q < PT; q++) {
            int j = q * 256 + t;
            float di = sqd(sp[j * 3], sp[j * 3 + 1], sp[j * 3 + 2], sx, sy, sz);
            d[q] = fminf(d[q], di);
        }
    }
}

// ---------------------------------------------------------------------------
__global__ void gather_kernel(
        const float* __restrict__ pos_in, const float* __restrict__ x_in,
        const int* __restrict__ s, int Nin, int M, int C,
        float* __restrict__ pos_out, float* __restrict__ x_out) {
    int b = blockIdx.y, m = blockIdx.x, t = threadIdx.x;
    int j = s[b * M + m];
    x_out[((size_t)b * M + m) * C + t] = x_in[((size_t)b * Nin + j) * C + t];
    if (t < 3) pos_out[((size_t)b * M + m) * 3 + t] = pos_in[((size_t)b * Nin + j) * 3 + t];
}

// ---------------------------------------------------------------------------
// Global max pool + MLP head + log_softmax (fp32).
// ---------------------------------------------------------------------------
__global__ __launch_bounds__(256) void head_kernel(
        const float* __restrict__ x3,
        const float* __restrict__ Wl1, const float* __restrict__ bl1,
        const float* __restrict__ Wl2, const float* __restrict__ bl2,
        const float* __restrict__ Wl3, const float* __restrict__ bl3,
        float* __restrict__ out) {
    __shared__ float gbuf[256], h1[256], h2[256], h3[40];
    int b = blockIdx.x, c = threadIdx.x;
    const float* xb = x3 + (size_t)b * 256 * 256;
    float m = -INFINITY;
    for (int r = 0; r < 256; r++) m = fmaxf(m, xb[r * 256 + c]);
    gbuf[c] = m;
    __syncthreads();
    float a = bl1[c];
    for (int k = 0; k < 256; k++) a = fmaf(gbuf[k], Wl1[k * 256 + c], a);
    h1[c] = fmaxf(a, 0.f);
    __syncthreads();
    a = bl2[c];
    for (int k = 0; k < 256; k++) a = fmaf(h1[k], Wl2[k * 256 + c], a);
    h2[c] = fmaxf(a, 0.f);
    __syncthreads();
    if (c < 40) {
        a = bl3[c];
        for (int k = 0; k < 256; k++) a = fmaf(h2[k], Wl3[k * 40 + c], a);
        h3[c] = a;
    }
    __syncthreads();
    if (c < 64) {
        float v = -INFINITY;
        if (c < 40) v = h3[c];
        float mx = v;
#pragma unroll
        for (int off = 32; off >= 1; off >>= 1) mx = fmaxf(mx, __shfl_xor(mx, off, 64));
        float e = (c < 40) ? expf(__fsub_rn(v, mx)) : 0.f;
        float s = e;
#pragma unroll
        for (int off = 32; off >= 1; off >>= 1) s = __fadd_rn(s, __shfl_xor(s, off, 64));
        float ls = logf(s);
        if (c < 40) out[b * 40 + c] = __fsub_rn(__fsub_rn(v, mx), ls);
    }
}

// ---------------------------------------------------------------------------
extern "C" void kernel_launch(void* const* d_in, const int* in_sizes, int n_in,
                              void* d_out, int out_size, void* d_ws, size_t ws_size,
                              hipStream_t stream) {
    (void)in_sizes; (void)n_in; (void)out_size; (void)ws_size;
    const float* pos = (const float*)d_in[0];
    const float* W1a = (const float*)d_in[2];
    const float* b1a = (const float*)d_in[3];
    const float* W1b = (const float*)d_in[4];
    const float* b1b = (const float*)d_in[5];
    const float* W2a = (const float*)d_in[6];
    const float* b2a = (const float*)d_in[7];
    const float* W2b = (const float*)d_in[8];
    const float* b2b = (const float*)d_in[9];
    const float* W3a = (const float*)d_in[10];
    const float* b3a = (const float*)d_in[11];
    const float* W3b = (const float*)d_in[12];
    const float* b3b = (const float*)d_in[13];
    const float* Wl1 = (const float*)d_in[14];
    const float* bl1 = (const float*)d_in[15];
    const float* Wl2 = (const float*)d_in[16];
    const float* bl2 = (const float*)d_in[17];
    const float* Wl3 = (const float*)d_in[18];
    const float* bl3 = (const float*)d_in[19];
    float* out = (float*)d_out;

    const int B = 32;
    char* w = (char*)d_ws;
    auto alloc = [&](size_t bytes) -> char* {
        char* r = w;
        w += (bytes + 255) & ~(size_t)255;
        return r;
    };
    int*   idx1 = (int*)  alloc((size_t)B * 2048 * 33 * 4);
    float* x1   = (float*)alloc((size_t)B * 2048 * 64 * 4);
    int*   s1   = (int*)  alloc((size_t)B * 1024 * 4);
    float* pos2 = (float*)alloc((size_t)B * 1024 * 3 * 4);
    float* x2in = (float*)alloc((size_t)B * 1024 * 64 * 4);
    int*   idx2 = (int*)  alloc((size_t)B * 1024 * 33 * 4);
    float* x2   = (float*)alloc((size_t)B * 1024 * 128 * 4);
    int*   s2   = (int*)  alloc((size_t)B * 256 * 4);
    float* pos3 = (float*)alloc((size_t)B * 256 * 3 * 4);
    float* x3in = (float*)alloc((size_t)B * 256 * 128 * 4);
    int*   idx3 = (int*)  alloc((size_t)B * 256 * 33 * 4);
    float* x3   = (float*)alloc((size_t)B * 256 * 256 * 4);
    // packed bf16 weight fragments
    short* Wp1a = (short*)alloc(4  * 1 * 64 * 8 * 2);
    short* Wp1b = (short*)alloc(4  * 2 * 64 * 8 * 2);
    short* Wp2a = (short*)alloc(8  * 3 * 64 * 8 * 2);
    short* Wp2b = (short*)alloc(8  * 4 * 64 * 8 * 2);
    short* Wp3a = (short*)alloc(16 * 5 * 64 * 8 * 2);
    short* Wp3b = (short*)alloc(16 * 8 * 64 * 8 * 2);

    // weight packing (tiny, once per launch)
    pack_w_kernel<<<1,  256, 0, stream>>>(W1a, Wp1a, 3,   64,  1, 256);
    pack_w_kernel<<<2,  256, 0, stream>>>(W1b, Wp1b, 64,  64,  2, 512);
    pack_w_kernel<<<6,  256, 0, stream>>>(W2a, Wp2a, 67,  128, 3, 1536);
    pack_w_kernel<<<8,  256, 0, stream>>>(W2b, Wp2b, 128, 128, 4, 2048);
    pack_w_kernel<<<20, 256, 0, stream>>>(W3a, Wp3a, 131, 256, 5, 5120);
    pack_w_kernel<<<32, 256, 0, stream>>>(W3b, Wp3b, 256, 256, 8, 8192);

    // ---- SA module 1 (2048 pts, r=0.2) ----
    radius_kernel<<<dim3(B, 8), 256, 0, stream>>>(pos, 2048, 0.04f, idx1);
    conv_mfma_kernel<0, 64, 4, 2048><<<B * 2048 / 4, 256, 0, stream>>>(
        pos, nullptr, idx1, Wp1a, b1a, Wp1b, b1b, x1);
    fps_kernel<2048, 1024, 8><<<B, 256, 0, stream>>>(pos, s1);
    gather_kernel<<<dim3(1024, B), 64, 0, stream>>>(pos, x1, s1, 2048, 1024, 64, pos2, x2in);

    // ---- SA module 2 (1024 pts, r=0.4) ----
    radius_kernel<<<dim3(B, 4), 256, 0, stream>>>(pos2, 1024, 0.16f, idx2);
    conv_mfma_kernel<64, 128, 1, 1024><<<B * 1024, 256, 0, stream>>>(
        pos2, x2in, idx2, Wp2a, b2a, Wp2b, b2b, x2);
    fps_kernel<1024, 256, 4><<<B, 256, 0, stream>>>(pos2, s2);
    gather_kernel<<<dim3(256, B), 128, 0, stream>>>(pos2, x2, s2, 1024, 256, 128, pos3, x3in);

    // ---- SA module 3 (256 pts, r=1.0) ----
    radius_kernel<<<dim3(B, 1), 256, 0, stream>>>(pos3, 256, 1.0f, idx3);
    conv_mfma_kernel<128, 256, 1, 256><<<B * 256, 256, 0, stream>>>(
        pos3, x3in, idx3, Wp3a, b3a, Wp3b, b3b, x3);

    // ---- global pool + head ----
    head_kernel<<<B, 256, 0, stream>>>(x3, Wl1, bl1, Wl2, bl2, Wl3, bl3, out);
}

// Round 3
// 2848.773 us; speedup vs baseline: 5.3642x; 2.1233x over previous
//
#include <hip/hip_runtime.h>
#include <math.h>

#define DEV static __device__ __forceinline__

typedef short s8v  __attribute__((ext_vector_type(8)));   // 8 bf16 (A/B frag)
typedef short s4v  __attribute__((ext_vector_type(4)));
typedef float f4v  __attribute__((ext_vector_type(4)));   // C/D frag

// round-to-nearest-even f32 -> bf16 (bits in a short)
DEV short bf16rne(float f) {
    unsigned u = __float_as_uint(f);
    unsigned r = (u + 0x7fffu + ((u >> 16) & 1u)) >> 16;
    return (short)r;
}

// Exact-IEEE squared distance, same op order as the numpy/XLA reference.
DEV float sqd(float ax, float ay, float az, float bx, float by, float bz) {
    float dx = __fsub_rn(ax, bx), dy = __fsub_rn(ay, by), dz = __fsub_rn(az, bz);
    return __fadd_rn(__fadd_rn(__fmul_rn(dx, dx), __fmul_rn(dy, dy)), __fmul_rn(dz, dz));
}

// ---------------------------------------------------------------------------
// Radius top-k, one WAVE per query. Each lane owns Q=N/64 strided candidates,
// packs key (d2_bits<<32)|j (lexicographic: d2 asc, ties -> lower j, exactly
// lax.top_k stability), bitonic-sorts its keys in registers, then 32 rounds
// of wave-min extraction. Selection math is exact-IEEE fp32 (bit-identical to
// the reference). Output row of 33 ints: packed neighbors, self, -1 padding.
// ---------------------------------------------------------------------------
template <int N>
__global__ __launch_bounds__(256) void radius_topk_kernel(
        const float* __restrict__ pos, float rr, int* __restrict__ idx_out) {
    constexpr int Q = N / 64;
    constexpr unsigned long long INV = ~0ull;
    int b = blockIdx.x;
    int wid = threadIdx.x >> 6, lane = threadIdx.x & 63;
    int i = blockIdx.y * 4 + wid;
    const float* p = pos + (size_t)b * N * 3;
    float qx = p[i * 3 + 0], qy = p[i * 3 + 1], qz = p[i * 3 + 2];

    unsigned long long c[Q];
#pragma unroll
    for (int q = 0; q < Q; q++) {
        int jj = q * 64 + lane;
        float px = p[jj * 3 + 0], py = p[jj * 3 + 1], pz = p[jj * 3 + 2];
        float d2 = sqd(px, py, pz, qx, qy, qz);
        bool valid = (jj != i) && (d2 <= rr);
        c[q] = valid ? ((((unsigned long long)__float_as_uint(d2)) << 32)
                        | (unsigned)jj)
                     : INV;
    }

    // per-lane bitonic sort (ascending), all indices compile-time
#pragma unroll
    for (int k = 2; k <= Q; k <<= 1) {
#pragma unroll
        for (int jj = k >> 1; jj > 0; jj >>= 1) {
#pragma unroll
            for (int t = 0; t < Q; t++) {
                int l = t ^ jj;
                if (l > t) {
                    bool up = ((t & k) == 0);
                    unsigned long long a = c[t], d = c[l];
                    bool sw = (a > d) != up;
                    c[t] = sw ? d : a;
                    c[l] = sw ? a : d;
                }
            }
        }
    }

    int* orow = idx_out + ((size_t)b * N + i) * 33;
    int cnt = 0;
    for (int s = 0; s < 32; s++) {
        unsigned long long h = c[0];
        unsigned long long g = h;
#pragma unroll
        for (int off = 1; off < 64; off <<= 1) {
            unsigned long long o = __shfl_xor(g, off, 64);
            g = (o < g) ? o : g;
        }
        if (lane == 0) orow[s] = (int)(unsigned)(g & 0xffffffffull);
        cnt += (g != INV) ? 1 : 0;
        if (h == g && g != INV) {   // unique winner pops its sorted head
#pragma unroll
            for (int q = 0; q < Q - 1; q++) c[q] = c[q + 1];
            c[Q - 1] = INV;
        }
    }
    if (lane == 0) {
        if (cnt < 32) orow[cnt] = i;           // self-loop slot
        orow[32] = (cnt == 32) ? i : -1;
    }
}

// ---------------------------------------------------------------------------
// Weight pre-pack: W [K x C] f32 row-major -> bf16 A-fragments of W^T for
// mfma_f32_16x16x32_bf16. Layout: frag[mt][ks][lane][j]:
//   c = 16*mt + (lane&15), k = 32*ks + (lane>>4)*8 + j, elem = W[k*C+c] (0 pad).
// ---------------------------------------------------------------------------
__global__ void pack_w_kernel(const float* __restrict__ W, short* __restrict__ out,
                              int Kreal, int C, int KS, int total) {
    int t = blockIdx.x * 256 + threadIdx.x;
    if (t >= total) return;
    int lane = t & 63;
    int mk = t >> 6;
    int ks = mk % KS, mt = mk / KS;
    int c = 16 * mt + (lane & 15);
    int k0 = 32 * ks + ((lane >> 4) << 3);
    s8v v;
#pragma unroll
    for (int j = 0; j < 8; j++) {
        int k = k0 + j;
        v[j] = (k < Kreal) ? bf16rne(W[(size_t)k * C + c]) : (short)0;
    }
    *(s8v*)(out + (size_t)t * 8) = v;
}

// ---------------------------------------------------------------------------
// Fused MFMA point-conv: out[i,:] = relu( max_valid_rows( relu(F@Wa+ba)@Wb+bb ) )
// ---------------------------------------------------------------------------
template <int CXIN, int CH, int PPB, int N>
__global__ __launch_bounds__(256) void conv_mfma_kernel(
        const float* __restrict__ pos, const float* __restrict__ xin,
        const int* __restrict__ idx,
        const short* __restrict__ Wpa, const float* __restrict__ ba,
        const short* __restrict__ Wpb, const float* __restrict__ bb,
        float* __restrict__ xout) {
    constexpr int CIN  = CXIN + 3;
    constexpr int CINp = (CIN + 31) & ~31;
    constexpr int KS1  = CINp / 32, KS2 = CH / 32;
    constexpr int MT   = CH / 16;
    constexpr int MTW  = (PPB == 4) ? MT : MT / 4;   // channel tiles per wave
    constexpr int RP   = 48;                          // padded rows per point
    constexpr int NT   = 3;                           // row tiles per point
    constexpr int FS   = CINp * 2 + 16;               // F row stride (bytes), FS/16 odd
    constexpr int HS   = CH * 2 + 16;                 // H1 row stride (bytes), HS/16 odd
    __shared__ __align__(16) char Fs[PPB * RP * FS];
    __shared__ __align__(16) char Hs[PPB * RP * HS];
    __shared__ int sj[PPB * RP];

    int tid = threadIdx.x;
    int lane = tid & 63, wid = tid >> 6;
    int pid0 = blockIdx.x * PPB;

    for (int r = tid; r < PPB * RP; r += 256) {
        int p = r / RP, s = r - p * RP;
        sj[r] = (s < 33) ? idx[(size_t)(pid0 + p) * 33 + s] : -1;
    }
    __syncthreads();

    // ---- build F (gathered neighbor features, bf16, zero-padded) ----
    constexpr int FE = PPB * RP * CINp;
    for (int e = tid; e < FE; e += 256) {
        int r = e / CINp, f = e - r * CINp;
        int p = r / RP;
        int pid = pid0 + p;
        int b = pid / N, i = pid - b * N;
        int j = sj[r];
        float v = 0.f;
        if (j >= 0 && f < CIN) {
            if (f < CXIN) {
                v = xin[((size_t)b * N + j) * CXIN + f];
            } else {
                int a = f - CXIN;
                v = __fsub_rn(pos[((size_t)b * N + j) * 3 + a],
                              pos[((size_t)b * N + i) * 3 + a]);
            }
        }
        *(short*)(Fs + (size_t)r * FS + f * 2) = bf16rne(v);
    }
    __syncthreads();

    int pw  = (PPB == 4) ? wid : 0;          // point this wave works on
    int mt0 = (PPB == 4) ? 0 : wid * MTW;    // first output-channel tile
    const char* Fw = Fs + pw * RP * FS;
    char* Hw = Hs + pw * RP * HS;
    int lr = lane & 15, lg = lane >> 4;      // row-within-tile, k-group

    // ---- GEMM1: H1^T tiles = WaT x F^T ----
    f4v acc[MTW][NT];
#pragma unroll
    for (int m = 0; m < MTW; m++)
#pragma unroll
        for (int nt = 0; nt < NT; nt++)
#pragma unroll
            for (int q = 0; q < 4; q++) acc[m][nt][q] = 0.f;
#pragma unroll
    for (int ks = 0; ks < KS1; ks++) {
        s8v bfr[NT];
#pragma unroll
        for (int nt = 0; nt < NT; nt++)
            bfr[nt] = *(const s8v*)(Fw + (nt * 16 + lr) * FS + (32 * ks + lg * 8) * 2);
#pragma unroll
        for (int m = 0; m < MTW; m++) {
            s8v afr = *(const s8v*)(Wpa + (((size_t)(mt0 + m) * KS1 + ks) * 64 + lane) * 8);
#pragma unroll
            for (int nt = 0; nt < NT; nt++)
                acc[m][nt] = __builtin_amdgcn_mfma_f32_16x16x32_bf16(afr, bfr[nt], acc[m][nt], 0, 0, 0);
        }
    }
    // bias + relu -> H1 (bf16, row-major, b64 packed writes)
#pragma unroll
    for (int m = 0; m < MTW; m++) {
        int cbase = (mt0 + m) * 16 + lg * 4;
        f4v bv = *(const f4v*)(ba + cbase);
#pragma unroll
        for (int nt = 0; nt < NT; nt++) {
            s4v hq;
#pragma unroll
            for (int q = 0; q < 4; q++)
                hq[q] = bf16rne(fmaxf(acc[m][nt][q] + bv[q], 0.f));
            *(s4v*)(Hw + (nt * 16 + lr) * HS + cbase * 2) = hq;
        }
    }
    __syncthreads();

    // ---- GEMM2: out^T tiles = WbT x H1^T ----
    f4v acc2[MTW][NT];
#pragma unroll
    for (int m = 0; m < MTW; m++)
#pragma unroll
        for (int nt = 0; nt < NT; nt++)
#pragma unroll
            for (int q = 0; q < 4; q++) acc2[m][nt][q] = 0.f;
#pragma unroll
    for (int ks = 0; ks < KS2; ks++) {
        s8v bfr[NT];
#pragma unroll
        for (int nt = 0; nt < NT; nt++)
            bfr[nt] = *(const s8v*)(Hw + (nt * 16 + lr) * HS + (32 * ks + lg * 8) * 2);
#pragma unroll
        for (int m = 0; m < MTW; m++) {
            s8v afr = *(const s8v*)(Wpb + (((size_t)(mt0 + m) * KS2 + ks) * 64 + lane) * 8);
#pragma unroll
            for (int nt = 0; nt < NT; nt++)
                acc2[m][nt] = __builtin_amdgcn_mfma_f32_16x16x32_bf16(afr, bfr[nt], acc2[m][nt], 0, 0, 0);
        }
    }

    // ---- epilogue: bias, relu, masked max over valid rows, write ----
    const int* sjw = sj + pw * RP;
#pragma unroll
    for (int m = 0; m < MTW; m++) {
        int cbase = (mt0 + m) * 16 + lg * 4;
        f4v bv = *(const f4v*)(bb + cbase);
        f4v vmx;
#pragma unroll
        for (int q = 0; q < 4; q++) vmx[q] = 0.f;  // relu floor = safe neutral
#pragma unroll
        for (int nt = 0; nt < NT; nt++) {
            int s = nt * 16 + lr;
            bool valid = (s < 33) && (sjw[s] >= 0);
#pragma unroll
            for (int q = 0; q < 4; q++) {
                float v = fmaxf(acc2[m][nt][q] + bv[q], 0.f);
                if (valid) vmx[q] = fmaxf(vmx[q], v);
            }
        }
#pragma unroll
        for (int off = 1; off < 16; off <<= 1)
#pragma unroll
            for (int q = 0; q < 4; q++)
                vmx[q] = fmaxf(vmx[q], __shfl_xor(vmx[q], off, 64));
        if (lr == 0) {
            int pid = pid0 + pw;
            *(f4v*)(xout + (size_t)pid * CH + cbase) = vmx;
        }
    }
}

// ---------------------------------------------------------------------------
// Farthest point sampling (fp32 exact selection; ties -> lowest index).
// ---------------------------------------------------------------------------
template <int N, int M, int PT>
__global__ __launch_bounds__(256) void fps_kernel(
        const float* __restrict__ pos, int* __restrict__ s_out) {
    __shared__ float sp[N * 3];
    __shared__ float swv[4];
    __shared__ int swi[4];
    __shared__ float selp[3];
    int b = blockIdx.x;
    const float* p = pos + (size_t)b * N * 3;
    int t = threadIdx.x;
    for (int u = t; u < N * 3; u += 256) sp[u] = p[u];
    __syncthreads();
    float d[PT];
    float x0 = sp[0], y0 = sp[1], z0 = sp[2];
#pragma unroll
    for (int q = 0; q < PT; q++) {
        int j = q * 256 + t;
        d[q] = sqd(sp[j * 3], sp[j * 3 + 1], sp[j * 3 + 2], x0, y0, z0);
    }
    int* so = s_out + b * M;
    if (t == 0) so[0] = 0;
    for (int m = 1; m < M; m++) {
        float bv = d[0];
        int bj = t;
#pragma unroll
        for (int q = 1; q < PT; q++) {
            int j = q * 256 + t;
            if (d[q] > bv) { bv = d[q]; bj = j; }
        }
#pragma unroll
        for (int off = 32; off >= 1; off >>= 1) {
            float ov = __shfl_xor(bv, off, 64);
            int oj = __shfl_xor(bj, off, 64);
            if (ov > bv || (ov == bv && oj < bj)) { bv = ov; bj = oj; }
        }
        int w = t >> 6;
        if ((t & 63) == 0) { swv[w] = bv; swi[w] = bj; }
        __syncthreads();
        if (t == 0) {
            float v = swv[0];
            int j = swi[0];
            for (int ww = 1; ww < 4; ww++)
                if (swv[ww] > v || (swv[ww] == v && swi[ww] < j)) { v = swv[ww]; j = swi[ww]; }
            so[m] = j;
            selp[0] = sp[j * 3]; selp[1] = sp[j * 3 + 1]; selp[2] = sp[j * 3 + 2];
        }
        __syncthreads();
        float sx = selp[0], sy = selp[1], sz = selp[2];
#pragma unroll
        for (int q = 0; q < PT; q++) {
            int j = q * 256 + t;
            float di = sqd(sp[j * 3], sp[j * 3 + 1], sp[j * 3 + 2], sx, sy, sz);
            d[q] = fminf(d[q], di);
        }
    }
}

// ---------------------------------------------------------------------------
__global__ void gather_kernel(
        const float* __restrict__ pos_in, const float* __restrict__ x_in,
        const int* __restrict__ s, int Nin, int M, int C,
        float* __restrict__ pos_out, float* __restrict__ x_out) {
    int b = blockIdx.y, m = blockIdx.x, t = threadIdx.x;
    int j = s[b * M + m];
    x_out[((size_t)b * M + m) * C + t] = x_in[((size_t)b * Nin + j) * C + t];
    if (t < 3) pos_out[((size_t)b * M + m) * 3 + t] = pos_in[((size_t)b * Nin + j) * 3 + t];
}

// ---------------------------------------------------------------------------
// Global max pool + MLP head + log_softmax (fp32).
// ---------------------------------------------------------------------------
__global__ __launch_bounds__(256) void head_kernel(
        const float* __restrict__ x3,
        const float* __restrict__ Wl1, const float* __restrict__ bl1,
        const float* __restrict__ Wl2, const float* __restrict__ bl2,
        const float* __restrict__ Wl3, const float* __restrict__ bl3,
        float* __restrict__ out) {
    __shared__ float gbuf[256], h1[256], h2[256], h3[40];
    int b = blockIdx.x, c = threadIdx.x;
    const float* xb = x3 + (size_t)b * 256 * 256;
    float m = -INFINITY;
    for (int r = 0; r < 256; r++) m = fmaxf(m, xb[r * 256 + c]);
    gbuf[c] = m;
    __syncthreads();
    float a = bl1[c];
    for (int k = 0; k < 256; k++) a = fmaf(gbuf[k], Wl1[k * 256 + c], a);
    h1[c] = fmaxf(a, 0.f);
    __syncthreads();
    a = bl2[c];
    for (int k = 0; k < 256; k++) a = fmaf(h1[k], Wl2[k * 256 + c], a);
    h2[c] = fmaxf(a, 0.f);
    __syncthreads();
    if (c < 40) {
        a = bl3[c];
        for (int k = 0; k < 256; k++) a = fmaf(h2[k], Wl3[k * 40 + c], a);
        h3[c] = a;
    }
    __syncthreads();
    if (c < 64) {
        float v = -INFINITY;
        if (c < 40) v = h3[c];
        float mx = v;
#pragma unroll
        for (int off = 32; off >= 1; off >>= 1) mx = fmaxf(mx, __shfl_xor(mx, off, 64));
        float e = (c < 40) ? expf(__fsub_rn(v, mx)) : 0.f;
        float s = e;
#pragma unroll
        for (int off = 32; off >= 1; off >>= 1) s = __fadd_rn(s, __shfl_xor(s, off, 64));
        float ls = logf(s);
        if (c < 40) out[b * 40 + c] = __fsub_rn(__fsub_rn(v, mx), ls);
    }
}

// ---------------------------------------------------------------------------
extern "C" void kernel_launch(void* const* d_in, const int* in_sizes, int n_in,
                              void* d_out, int out_size, void* d_ws, size_t ws_size,
                              hipStream_t stream) {
    (void)in_sizes; (void)n_in; (void)out_size; (void)ws_size;
    const float* pos = (const float*)d_in[0];
    const float* W1a = (const float*)d_in[2];
    const float* b1a = (const float*)d_in[3];
    const float* W1b = (const float*)d_in[4];
    const float* b1b = (const float*)d_in[5];
    const float* W2a = (const float*)d_in[6];
    const float* b2a = (const float*)d_in[7];
    const float* W2b = (const float*)d_in[8];
    const float* b2b = (const float*)d_in[9];
    const float* W3a = (const float*)d_in[10];
    const float* b3a = (const float*)d_in[11];
    const float* W3b = (const float*)d_in[12];
    const float* b3b = (const float*)d_in[13];
    const float* Wl1 = (const float*)d_in[14];
    const float* bl1 = (const float*)d_in[15];
    const float* Wl2 = (const float*)d_in[16];
    const float* bl2 = (const float*)d_in[17];
    const float* Wl3 = (const float*)d_in[18];
    const float* bl3 = (const float*)d_in[19];
    float* out = (float*)d_out;

    const int B = 32;
    char* w = (char*)d_ws;
    auto alloc = [&](size_t bytes) -> char* {
        char* r = w;
        w += (bytes + 255) & ~(size_t)255;
        return r;
    };
    int*   idx1 = (int*)  alloc((size_t)B * 2048 * 33 * 4);
    float* x1   = (float*)alloc((size_t)B * 2048 * 64 * 4);
    int*   s1   = (int*)  alloc((size_t)B * 1024 * 4);
    float* pos2 = (float*)alloc((size_t)B * 1024 * 3 * 4);
    float* x2in = (float*)alloc((size_t)B * 1024 * 64 * 4);
    int*   idx2 = (int*)  alloc((size_t)B * 1024 * 33 * 4);
    float* x2   = (float*)alloc((size_t)B * 1024 * 128 * 4);
    int*   s2   = (int*)  alloc((size_t)B * 256 * 4);
    float* pos3 = (float*)alloc((size_t)B * 256 * 3 * 4);
    float* x3in = (float*)alloc((size_t)B * 256 * 128 * 4);
    int*   idx3 = (int*)  alloc((size_t)B * 256 * 33 * 4);
    float* x3   = (float*)alloc((size_t)B * 256 * 256 * 4);
    // packed bf16 weight fragments
    short* Wp1a = (short*)alloc(4  * 1 * 64 * 8 * 2);
    short* Wp1b = (short*)alloc(4  * 2 * 64 * 8 * 2);
    short* Wp2a = (short*)alloc(8  * 3 * 64 * 8 * 2);
    short* Wp2b = (short*)alloc(8  * 4 * 64 * 8 * 2);
    short* Wp3a = (short*)alloc(16 * 5 * 64 * 8 * 2);
    short* Wp3b = (short*)alloc(16 * 8 * 64 * 8 * 2);

    // weight packing (tiny, once per launch)
    pack_w_kernel<<<1,  256, 0, stream>>>(W1a, Wp1a, 3,   64,  1, 256);
    pack_w_kernel<<<2,  256, 0, stream>>>(W1b, Wp1b, 64,  64,  2, 512);
    pack_w_kernel<<<6,  256, 0, stream>>>(W2a, Wp2a, 67,  128, 3, 1536);
    pack_w_kernel<<<8,  256, 0, stream>>>(W2b, Wp2b, 128, 128, 4, 2048);
    pack_w_kernel<<<20, 256, 0, stream>>>(W3a, Wp3a, 131, 256, 5, 5120);
    pack_w_kernel<<<32, 256, 0, stream>>>(W3b, Wp3b, 256, 256, 8, 8192);

    // ---- SA module 1 (2048 pts, r=0.2) ----
    radius_topk_kernel<2048><<<dim3(B, 512), 256, 0, stream>>>(pos, 0.04f, idx1);
    conv_mfma_kernel<0, 64, 4, 2048><<<B * 2048 / 4, 256, 0, stream>>>(
        pos, nullptr, idx1, Wp1a, b1a, Wp1b, b1b, x1);
    fps_kernel<2048, 1024, 8><<<B, 256, 0, stream>>>(pos, s1);
    gather_kernel<<<dim3(1024, B), 64, 0, stream>>>(pos, x1, s1, 2048, 1024, 64, pos2, x2in);

    // ---- SA module 2 (1024 pts, r=0.4) ----
    radius_topk_kernel<1024><<<dim3(B, 256), 256, 0, stream>>>(pos2, 0.16f, idx2);
    conv_mfma_kernel<64, 128, 1, 1024><<<B * 1024, 256, 0, stream>>>(
        pos2, x2in, idx2, Wp2a, b2a, Wp2b, b2b, x2);
    fps_kernel<1024, 256, 4><<<B, 256, 0, stream>>>(pos2, s2);
    gather_kernel<<<dim3(256, B), 128, 0, stream>>>(pos2, x2, s2, 1024, 256, 128, pos3, x3in);

    // ---- SA module 3 (256 pts, r=1.0) ----
    radius_topk_kernel<256><<<dim3(B, 64), 256, 0, stream>>>(pos3, 1.0f, idx3);
    conv_mfma_kernel<128, 256, 1, 256><<<B * 256, 256, 0, stream>>>(
        pos3, x3in, idx3, Wp3a, b3a, Wp3b, b3b, x3);

    // ---- global pool + head ----
    head_kernel<<<B, 256, 0, stream>>>(x3, Wl1, bl1, Wl2, bl2, Wl3, bl3, out);
}